// Round 1
// baseline (1240.619 us; speedup 1.0000x reference)
//
#include <hip/hip_runtime.h>
#include <math.h>

#define B_  8
#define S_  4096
#define D_  768     // DIM == D_INNER == 768
#define K_  16      // KK
#define C_  48      // CD
#define N_  16      // NS
#define M_  (B_*S_) // 32768 rows

// C[m,n] = sum_k A[m,k] * Bm[n,k] + bias[n]
// A: (M,K) row-major; Bm: (N,K) row-major (i.e. the "B^T" GEMM)
template<int BM, int BN, int BK>
__global__ __launch_bounds__(256)
void gemm_bt(const float* __restrict__ A, const float* __restrict__ Bm,
             const float* __restrict__ bias, float* __restrict__ Cc,
             int M, int N, int K)
{
  __shared__ float As[BK][BM + 4];   // stride 132 floats: 16B-aligned rows, conflict-free
  __shared__ float Bs[BK][BN + 4];
  const int tid = threadIdx.x;
  const int tx  = tid & 15;   // n direction
  const int ty  = tid >> 4;   // m direction
  const int bm  = blockIdx.y * BM;
  const int bn  = blockIdx.x * BN;

  float acc[8][8];
#pragma unroll
  for (int i = 0; i < 8; ++i)
#pragma unroll
    for (int j = 0; j < 8; ++j) acc[i][j] = 0.f;

  for (int k0 = 0; k0 < K; k0 += BK) {
#pragma unroll
    for (int i = 0; i < BM / 64; ++i) {
      const int r  = (tid >> 2) + i * 64;
      const int cb = (tid & 3) * 4;
      float4 va = *reinterpret_cast<const float4*>(&A [(size_t)(bm + r) * K + k0 + cb]);
      As[cb + 0][r] = va.x; As[cb + 1][r] = va.y; As[cb + 2][r] = va.z; As[cb + 3][r] = va.w;
      float4 vb = *reinterpret_cast<const float4*>(&Bm[(size_t)(bn + r) * K + k0 + cb]);
      Bs[cb + 0][r] = vb.x; Bs[cb + 1][r] = vb.y; Bs[cb + 2][r] = vb.z; Bs[cb + 3][r] = vb.w;
    }
    __syncthreads();
#pragma unroll
    for (int k = 0; k < BK; ++k) {
      float a[8], b[8];
      *reinterpret_cast<float4*>(&a[0]) = *reinterpret_cast<const float4*>(&As[k][ty * 8]);
      *reinterpret_cast<float4*>(&a[4]) = *reinterpret_cast<const float4*>(&As[k][ty * 8 + 4]);
      *reinterpret_cast<float4*>(&b[0]) = *reinterpret_cast<const float4*>(&Bs[k][tx * 8]);
      *reinterpret_cast<float4*>(&b[4]) = *reinterpret_cast<const float4*>(&Bs[k][tx * 8 + 4]);
#pragma unroll
      for (int i = 0; i < 8; ++i)
#pragma unroll
        for (int j = 0; j < 8; ++j) acc[i][j] = fmaf(a[i], b[j], acc[i][j]);
    }
    __syncthreads();
  }

  float bb[8];
  *reinterpret_cast<float4*>(&bb[0]) = *reinterpret_cast<const float4*>(&bias[bn + tx * 8]);
  *reinterpret_cast<float4*>(&bb[4]) = *reinterpret_cast<const float4*>(&bias[bn + tx * 8 + 4]);
#pragma unroll
  for (int i = 0; i < 8; ++i) {
    const int m = bm + ty * 8 + i;
    float4 o;
    o.x = acc[i][0] + bb[0]; o.y = acc[i][1] + bb[1];
    o.z = acc[i][2] + bb[2]; o.w = acc[i][3] + bb[3];
    *reinterpret_cast<float4*>(&Cc[(size_t)m * N + bn + tx * 8]) = o;
    o.x = acc[i][4] + bb[4]; o.y = acc[i][5] + bb[5];
    o.z = acc[i][6] + bb[6]; o.w = acc[i][7] + bb[7];
    *reinterpret_cast<float4*>(&Cc[(size_t)m * N + bn + tx * 8 + 4]) = o;
  }
}

// Fused middle: u = silu(depthwise-conv3(u0) + conv_b); d = softplus(delta + dbias);
// s = sum_n A[k,c,n] * B_t*C_t; yT[b, l, c] = d*d*u*s   (transposed store, ready for GEMM2)
__global__ __launch_bounds__(256)
void fuse_mid(const float* __restrict__ u0, const float* __restrict__ delta,
              const float* __restrict__ Bt, const float* __restrict__ Ct,
              const float* __restrict__ Alog, const float* __restrict__ convw,
              const float* __restrict__ convb, const float* __restrict__ dbias,
              float* __restrict__ yT)
{
  __shared__ float G [N_][128];       // B*C products
  __shared__ float Ak[C_][17];        // A rows for this k (pad 17: conflict-free)
  __shared__ float Dt[C_][129];       // softplus(delta+bias) (pad 129)
  __shared__ float U0[130][C_];       // u0 tile with halo rows
  __shared__ float Wk[C_][3];
  __shared__ float CB[C_];

  const int tid = threadIdx.x;
  const int lt = blockIdx.x, k = blockIdx.y, b = blockIdx.z;
  const int l0 = lt * 128;

  for (int idx = tid; idx < N_ * 128; idx += 256) {
    const int n = idx >> 7, dl = idx & 127;
    const size_t g = (((size_t)b * K_ + k) * N_ + n) * S_ + l0 + dl;
    G[n][dl] = Bt[g] * Ct[g];
  }
  for (int idx = tid; idx < C_ * N_; idx += 256)
    Ak[idx >> 4][idx & 15] = Alog[(size_t)k * C_ * N_ + idx];
  if (tid < C_) {
    const int c = tid;
    Wk[c][0] = convw[(k * C_ + c) * 9 + 1];  // kh=0, kw=1 (only valid kw)
    Wk[c][1] = convw[(k * C_ + c) * 9 + 4];  // kh=1
    Wk[c][2] = convw[(k * C_ + c) * 9 + 7];  // kh=2
    CB[c]    = convb[k * C_ + c];
  }
  for (int idx = tid; idx < C_ * 128; idx += 256) {
    const int c = idx >> 7, dl = idx & 127;
    const float v = delta[((size_t)b * D_ + k * C_ + c) * S_ + l0 + dl] + dbias[k * C_ + c];
    Dt[c][dl] = (v > 20.f) ? v : log1pf(expf(v));   // softplus
  }
  for (int idx = tid; idx < 130 * C_; idx += 256) {
    const int l = idx / C_, c = idx % C_;
    const int gl = l0 + l - 1;
    float v = 0.f;
    if (gl >= 0 && gl < S_) v = u0[((size_t)b * S_ + gl) * D_ + k * C_ + c];
    U0[l][c] = v;
  }
  __syncthreads();

  for (int e = tid; e < C_ * 128; e += 256) {
    const int c = e % C_, dl = e / C_;      // c fastest -> coalesced store
    float x = fmaf(Wk[c][0], U0[dl][c],
              fmaf(Wk[c][1], U0[dl + 1][c],
              fmaf(Wk[c][2], U0[dl + 2][c], CB[c])));
    const float u = x / (1.f + expf(-x));   // silu
    const float d = Dt[c][dl];
    float s = 0.f;
#pragma unroll
    for (int n = 0; n < N_; ++n) s = fmaf(Ak[c][n], G[n][dl], s);
    yT[((size_t)b * S_ + l0 + dl) * D_ + k * C_ + c] = d * d * u * s;
  }
}

extern "C" void kernel_launch(void* const* d_in, const int* in_sizes, int n_in,
                              void* d_out, int out_size, void* d_ws, size_t ws_size,
                              hipStream_t stream) {
  const float* x      = (const float*)d_in[0];
  const float* in_w   = (const float*)d_in[1];   // (1536,768) — only rows [0,768) used
  const float* in_b   = (const float*)d_in[2];
  const float* convw  = (const float*)d_in[3];
  const float* convb  = (const float*)d_in[4];
  const float* out_w  = (const float*)d_in[5];
  const float* out_b  = (const float*)d_in[6];
  const float* Alog   = (const float*)d_in[7];
  const float* delta  = (const float*)d_in[8];
  const float* Bt     = (const float*)d_in[9];
  const float* Ct     = (const float*)d_in[10];
  const float* dbias  = (const float*)d_in[11];
  float* out = (float*)d_out;

  float* u0 = (float*)d_ws;                  // (B,S,D) f32
  float* yT = u0 + (size_t)M_ * D_;          // (B,S,D) f32

  // GEMM1: u0 = x @ in_w[:768].T + in_b[:768]
  gemm_bt<128,128,16><<<dim3(D_/128, M_/128), 256, 0, stream>>>(x, in_w, in_b, u0, M_, D_, D_);
  // fused conv/silu/softplus/einsum/product, transposed store
  fuse_mid<<<dim3(S_/128, K_, B_), 256, 0, stream>>>(u0, delta, Bt, Ct, Alog, convw, convb, dbias, yT);
  // GEMM2: out = yT @ out_w.T + out_b
  gemm_bt<128,128,16><<<dim3(D_/128, M_/128), 256, 0, stream>>>(yT, out_w, out_b, out, M_, D_, D_);
}

// Round 2
// 322.455 us; speedup vs baseline: 3.8474x; 3.8474x over previous
//
#include <hip/hip_runtime.h>
#include <math.h>

#define B_  8
#define S_  4096
#define D_  768     // DIM == D_INNER == 768
#define K_  16      // KK
#define C_  48      // CD
#define N_  16      // NS
#define M_  (B_*S_) // 32768 rows

typedef float  f32x4  __attribute__((ext_vector_type(4)));
typedef __bf16 bf16x8 __attribute__((ext_vector_type(8)));

__device__ __forceinline__ ushort f2bf(float f) {
  uint u = __builtin_bit_cast(uint, f);
  u += 0x7FFFu + ((u >> 16) & 1u);      // round-to-nearest-even
  return (ushort)(u >> 16);
}
__device__ __forceinline__ float bf2f(ushort h) {
  return __builtin_bit_cast(float, (uint)h << 16);
}

// ---------------- f32 -> bf16 conversion (memory-bound, float4 in / ushort4 out)
__global__ __launch_bounds__(256)
void cvt_f32_bf16(const float* __restrict__ in, ushort* __restrict__ out, int n4) {
  const int stride = gridDim.x * 256;
  for (int i = blockIdx.x * 256 + threadIdx.x; i < n4; i += stride) {
    float4 v = *reinterpret_cast<const float4*>(in + (size_t)i * 4);
    ushort4 o;
    o.x = f2bf(v.x); o.y = f2bf(v.y); o.z = f2bf(v.z); o.w = f2bf(v.w);
    *reinterpret_cast<ushort4*>(out + (size_t)i * 4) = o;
  }
}

// ---------------- bf16 MFMA GEMM (m97 structure): C[m,n] = sum_k A[m,k]*Bm[n,k] + bias[n]
// A: (M,768) bf16 row-major; Bm: (768,768) bf16 row-major. 128x128 tile, BK=32,
// 4 waves, each wave a 64x64 sub-tile = 4x4 frags of 16x16x32.
template<bool OUT_BF16>
__global__ __launch_bounds__(256)
void gemm_mfma_bt(const ushort* __restrict__ A, const ushort* __restrict__ Bm,
                  const float* __restrict__ bias, void* __restrict__ Cc)
{
  __shared__ ushort As[128 * 32];   // 8 KB, linear row-major [row][k] (global_load_lds dest)
  __shared__ ushort Bs[128 * 32];

  const int tid  = threadIdx.x;
  const int wid  = tid >> 6, lane = tid & 63;
  const int wr   = wid >> 1, wc   = wid & 1;       // wave -> 64x64 quadrant
  const int lr   = lane & 15, lg  = lane >> 4;
  const int bm   = blockIdx.y * 128, bn = blockIdx.x * 128;
  const int srow = lane >> 2;                      // staging: row within 16-row chunk
  const int scol = (lane & 3) * 8;                 // staging: k-element offset

  f32x4 acc[4][4];
#pragma unroll
  for (int i = 0; i < 4; ++i)
#pragma unroll
    for (int j = 0; j < 4; ++j) acc[i][j] = (f32x4){0.f, 0.f, 0.f, 0.f};

  for (int k0 = 0; k0 < 768; k0 += 32) {
    // stage 128x32 bf16 A-tile and B-tile: 8 chunks of 1024B each, 2 per wave per matrix
#pragma unroll
    for (int jj = 0; jj < 2; ++jj) {
      const int j = wid * 2 + jj;
      const ushort* ga = A  + (size_t)(bm + j * 16 + srow) * 768 + k0 + scol;
      __builtin_amdgcn_global_load_lds(
          (const __attribute__((address_space(1))) void*)ga,
          (__attribute__((address_space(3))) void*)(As + j * 512), 16, 0, 0);
      const ushort* gb = Bm + (size_t)(bn + j * 16 + srow) * 768 + k0 + scol;
      __builtin_amdgcn_global_load_lds(
          (const __attribute__((address_space(1))) void*)gb,
          (__attribute__((address_space(3))) void*)(Bs + j * 512), 16, 0, 0);
    }
    __syncthreads();

    bf16x8 af[4], bfr[4];
    const int ab = (wr * 64 + lr) * 32 + lg * 8;
    const int bb = (wc * 64 + lr) * 32 + lg * 8;
#pragma unroll
    for (int mf = 0; mf < 4; ++mf) af[mf]  = *reinterpret_cast<const bf16x8*>(&As[ab + mf * 512]);
#pragma unroll
    for (int nf = 0; nf < 4; ++nf) bfr[nf] = *reinterpret_cast<const bf16x8*>(&Bs[bb + nf * 512]);
#pragma unroll
    for (int mf = 0; mf < 4; ++mf)
#pragma unroll
      for (int nf = 0; nf < 4; ++nf)
        acc[mf][nf] = __builtin_amdgcn_mfma_f32_16x16x32_bf16(af[mf], bfr[nf], acc[mf][nf], 0, 0, 0);
    __syncthreads();
  }

  // epilogue: C/D layout col = lane&15, row = (lane>>4)*4 + reg
#pragma unroll
  for (int nf = 0; nf < 4; ++nf) {
    const int n  = bn + wc * 64 + nf * 16 + lr;
    const float bv = bias[n];
#pragma unroll
    for (int mf = 0; mf < 4; ++mf) {
      const int m0 = bm + wr * 64 + mf * 16 + lg * 4;
#pragma unroll
      for (int r = 0; r < 4; ++r) {
        const float v = acc[mf][nf][r] + bv;
        if (OUT_BF16) ((ushort*)Cc)[(size_t)(m0 + r) * 768 + n] = f2bf(v);
        else          ((float*) Cc)[(size_t)(m0 + r) * 768 + n] = v;
      }
    }
  }
}

// ---------------- fused middle: conv3+silu, softplus, einsum, d*d*u*s, bf16 transposed store
// S-tile = 64 -> ~27 KB LDS -> 6 blocks/CU (was 61 KB -> 2)
__global__ __launch_bounds__(256)
void fuse_mid(const ushort* __restrict__ u0b, const float* __restrict__ delta,
              const float* __restrict__ Bt, const float* __restrict__ Ct,
              const float* __restrict__ Alog, const float* __restrict__ convw,
              const float* __restrict__ convb, const float* __restrict__ dbias,
              ushort* __restrict__ yT)
{
  __shared__ float  G [N_][64];    // 4 KB   B*C products
  __shared__ float  Ak[C_][17];    // 3.3 KB (pad 17 -> banks spread)
  __shared__ float  Dt[C_][65];    // 12.2 KB (pad 65 -> stride%32==1, conflict-free c-fast read)
  __shared__ ushort U0[66 * 48];   // 6.2 KB  bf16 u0 tile with halo
  __shared__ float  Wk[C_][3];
  __shared__ float  CB[C_];

  const int tid = threadIdx.x;
  const int lt = blockIdx.x, k = blockIdx.y, b = blockIdx.z;
  const int l0 = lt * 64;

  for (int idx = tid; idx < N_ * 64; idx += 256) {
    const int n = idx >> 6, dl = idx & 63;
    const size_t g = (((size_t)b * K_ + k) * N_ + n) * S_ + l0 + dl;
    G[n][dl] = Bt[g] * Ct[g];
  }
  for (int idx = tid; idx < C_ * N_; idx += 256)
    Ak[idx >> 4][idx & 15] = Alog[(size_t)k * C_ * N_ + idx];
  if (tid < C_) {
    Wk[tid][0] = convw[(k * C_ + tid) * 9 + 1];   // only kw=1 column is in-bounds (W=1, pad 1)
    Wk[tid][1] = convw[(k * C_ + tid) * 9 + 4];
    Wk[tid][2] = convw[(k * C_ + tid) * 9 + 7];
    CB[tid]    = convb[k * C_ + tid];
  }
  for (int idx = tid; idx < C_ * 64; idx += 256) {
    const int c = idx >> 6, dl = idx & 63;
    const float v = delta[((size_t)b * D_ + k * C_ + c) * S_ + l0 + dl] + dbias[k * C_ + c];
    Dt[c][dl] = (v > 15.f) ? v : log1pf(__expf(v));   // softplus
  }
  { // u0 halo tile: 66 rows x 48 bf16 = 24 uints/row, coalesced-ish
    const uint* usrc = reinterpret_cast<const uint*>(u0b);
    uint* ud = reinterpret_cast<uint*>(U0);
    for (int idx = tid; idx < 66 * 24; idx += 256) {
      const int l = idx / 24, j = idx - l * 24;
      const int gl = l0 + l - 1;
      uint v = 0;
      if (gl >= 0 && gl < S_) v = usrc[(size_t)((size_t)b * S_ + gl) * 384 + k * 24 + j];
      ud[l * 24 + j] = v;
    }
  }
  __syncthreads();

  for (int e = tid; e < C_ * 64; e += 256) {
    const int c = e % C_, dl = e / C_;     // c fastest -> coalesced bf16 store
    float x = fmaf(Wk[c][0], bf2f(U0[dl * 48 + c]),
              fmaf(Wk[c][1], bf2f(U0[(dl + 1) * 48 + c]),
              fmaf(Wk[c][2], bf2f(U0[(dl + 2) * 48 + c]), CB[c])));
    const float u = x / (1.f + __expf(-x));   // silu
    const float d = Dt[c][dl];
    float s = 0.f;
#pragma unroll
    for (int n = 0; n < N_; ++n) s = fmaf(Ak[c][n], G[n][dl], s);
    yT[((size_t)((size_t)b * S_ + l0 + dl)) * D_ + k * C_ + c] = f2bf(d * d * u * s);
  }
}

extern "C" void kernel_launch(void* const* d_in, const int* in_sizes, int n_in,
                              void* d_out, int out_size, void* d_ws, size_t ws_size,
                              hipStream_t stream) {
  const float* x      = (const float*)d_in[0];
  const float* in_w   = (const float*)d_in[1];   // (1536,768) — only rows [0,768) used
  const float* in_b   = (const float*)d_in[2];
  const float* convw  = (const float*)d_in[3];
  const float* convb  = (const float*)d_in[4];
  const float* out_w  = (const float*)d_in[5];
  const float* out_b  = (const float*)d_in[6];
  const float* Alog   = (const float*)d_in[7];
  const float* delta  = (const float*)d_in[8];
  const float* Bt     = (const float*)d_in[9];
  const float* Ct     = (const float*)d_in[10];
  const float* dbias  = (const float*)d_in[11];
  float* out = (float*)d_out;

  // workspace: all bf16 (ushort). 3*50.3MB + 2*1.2MB = 153.4 MB
  ushort* xb  = (ushort*)d_ws;
  ushort* u0b = xb  + (size_t)M_ * D_;
  ushort* yTb = u0b + (size_t)M_ * D_;
  ushort* wb1 = yTb + (size_t)M_ * D_;
  ushort* wb2 = wb1 + (size_t)D_ * D_;

  cvt_f32_bf16<<<2048, 256, 0, stream>>>(x,     xb,  M_ * D_ / 4);
  cvt_f32_bf16<<<576,  256, 0, stream>>>(in_w,  wb1, D_ * D_ / 4);   // first 768 rows only
  cvt_f32_bf16<<<576,  256, 0, stream>>>(out_w, wb2, D_ * D_ / 4);

  // GEMM1: u0 = x @ in_w[:768].T + in_b   (bf16 out)
  gemm_mfma_bt<true ><<<dim3(6, 256), 256, 0, stream>>>(xb, wb1, in_b, u0b);
  // fused conv/silu/softplus/einsum/product, bf16 transposed store
  fuse_mid<<<dim3(S_ / 64, K_, B_), 256, 0, stream>>>(u0b, delta, Bt, Ct, Alog, convw, convb, dbias, yTb);
  // GEMM2: out = yT @ out_w.T + out_b   (f32 out)
  gemm_mfma_bt<false><<<dim3(6, 256), 256, 0, stream>>>(yTb, wb2, out_b, out);
}

// Round 3
// 230.204 us; speedup vs baseline: 5.3892x; 1.4007x over previous
//
#include <hip/hip_runtime.h>
#include <math.h>

#define B_  8
#define S_  4096
#define D_  768     // DIM == D_INNER == 768
#define K_  16      // KK
#define C_  48      // CD
#define N_  16      // NS
#define M_  (B_*S_) // 32768 rows

typedef float  f32x4  __attribute__((ext_vector_type(4)));
typedef __bf16 bf16x8 __attribute__((ext_vector_type(8)));

__device__ __forceinline__ ushort f2bf(float f) {
  uint u = __builtin_bit_cast(uint, f);
  u += 0x7FFFu + ((u >> 16) & 1u);      // round-to-nearest-even
  return (ushort)(u >> 16);
}
__device__ __forceinline__ float bf2f(ushort h) {
  return __builtin_bit_cast(float, (uint)h << 16);
}

// ---------------- f32 -> bf16 conversion (memory-bound, float4 in / ushort4 out)
__global__ __launch_bounds__(256)
void cvt_f32_bf16(const float* __restrict__ in, ushort* __restrict__ out, int n4) {
  const int stride = gridDim.x * 256;
  for (int i = blockIdx.x * 256 + threadIdx.x; i < n4; i += stride) {
    float4 v = *reinterpret_cast<const float4*>(in + (size_t)i * 4);
    ushort4 o;
    o.x = f2bf(v.x); o.y = f2bf(v.y); o.z = f2bf(v.z); o.w = f2bf(v.w);
    *reinterpret_cast<ushort4*>(out + (size_t)i * 4) = o;
  }
}

// ---------------- bf16 MFMA GEMM (m97 structure): C[m,n] = sum_k A[m,k]*Bm[n,k] + bias[n]
// 1-D grid of 1536 blocks with XCD-aware swizzle (1536 % 8 == 0 -> bijective):
// each XCD gets 192 consecutive work items = 32 M-panels x 6 N-tiles -> A-panel L2 reuse.
template<bool OUT_BF16>
__global__ __launch_bounds__(256)
void gemm_mfma_bt(const ushort* __restrict__ A, const ushort* __restrict__ Bm,
                  const float* __restrict__ bias, void* __restrict__ Cc)
{
  __shared__ ushort As[128 * 32];   // 8 KB, linear row-major [row][k] (global_load_lds dest)
  __shared__ ushort Bs[128 * 32];

  const int lin = blockIdx.x;
  const int swz = (lin & 7) * 192 + (lin >> 3);   // XCD-contiguous work chunks
  const int bn  = (swz % 6) * 128;
  const int bm  = (swz / 6) * 128;

  const int tid  = threadIdx.x;
  const int wid  = tid >> 6, lane = tid & 63;
  const int wr   = wid >> 1, wc   = wid & 1;       // wave -> 64x64 quadrant
  const int lr   = lane & 15, lg  = lane >> 4;
  const int srow = lane >> 2;                      // staging: row within 16-row chunk
  const int scol = (lane & 3) * 8;                 // staging: k-element offset

  f32x4 acc[4][4];
#pragma unroll
  for (int i = 0; i < 4; ++i)
#pragma unroll
    for (int j = 0; j < 4; ++j) acc[i][j] = (f32x4){0.f, 0.f, 0.f, 0.f};

  for (int k0 = 0; k0 < 768; k0 += 32) {
    // stage 128x32 bf16 A-tile and B-tile: 8 chunks of 1024B each, 2 per wave per matrix
#pragma unroll
    for (int jj = 0; jj < 2; ++jj) {
      const int j = wid * 2 + jj;
      const ushort* ga = A  + (size_t)(bm + j * 16 + srow) * 768 + k0 + scol;
      __builtin_amdgcn_global_load_lds(
          (const __attribute__((address_space(1))) void*)ga,
          (__attribute__((address_space(3))) void*)(As + j * 512), 16, 0, 0);
      const ushort* gb = Bm + (size_t)(bn + j * 16 + srow) * 768 + k0 + scol;
      __builtin_amdgcn_global_load_lds(
          (const __attribute__((address_space(1))) void*)gb,
          (__attribute__((address_space(3))) void*)(Bs + j * 512), 16, 0, 0);
    }
    __syncthreads();

    bf16x8 af[4], bfr[4];
    const int ab = (wr * 64 + lr) * 32 + lg * 8;
    const int bb = (wc * 64 + lr) * 32 + lg * 8;
#pragma unroll
    for (int mf = 0; mf < 4; ++mf) af[mf]  = *reinterpret_cast<const bf16x8*>(&As[ab + mf * 512]);
#pragma unroll
    for (int nf = 0; nf < 4; ++nf) bfr[nf] = *reinterpret_cast<const bf16x8*>(&Bs[bb + nf * 512]);
#pragma unroll
    for (int mf = 0; mf < 4; ++mf)
#pragma unroll
      for (int nf = 0; nf < 4; ++nf)
        acc[mf][nf] = __builtin_amdgcn_mfma_f32_16x16x32_bf16(af[mf], bfr[nf], acc[mf][nf], 0, 0, 0);
    __syncthreads();
  }

  // epilogue: C/D layout col = lane&15, row = (lane>>4)*4 + reg
#pragma unroll
  for (int nf = 0; nf < 4; ++nf) {
    const int n  = bn + wc * 64 + nf * 16 + lr;
    const float bv = bias[n];
#pragma unroll
    for (int mf = 0; mf < 4; ++mf) {
      const int m0 = bm + wr * 64 + mf * 16 + lg * 4;
#pragma unroll
      for (int r = 0; r < 4; ++r) {
        const float v = acc[mf][nf][r] + bv;
        if (OUT_BF16) ((ushort*)Cc)[(size_t)(m0 + r) * 768 + n] = f2bf(v);
        else          ((float*) Cc)[(size_t)(m0 + r) * 768 + n] = v;
      }
    }
  }
}

// ---------------- fused middle: conv3+silu, softplus(delta), einsum, d*d*u*s, bf16 transposed store
// Wave-uniform c, dl = lane: G in registers, Ak broadcast-read, U0 transposed in LDS,
// delta read straight from global (coalesced), conflict-free everywhere.
#define U0P 68
#define YSP 70

__global__ __launch_bounds__(256)
void fuse_mid(const ushort* __restrict__ u0b, const float* __restrict__ delta,
              const float* __restrict__ Bt, const float* __restrict__ Ct,
              const float* __restrict__ Alog, const float* __restrict__ convw,
              const float* __restrict__ convb, const float* __restrict__ dbias,
              ushort* __restrict__ yT)
{
  __shared__ float  Gs [N_ * 64];       // [n][dl]  B*C products (4 KB)
  __shared__ float  Ak [C_ * N_];       // [c][n]   A rows (3 KB, broadcast reads)
  __shared__ ushort U0T[C_ * U0P];      // [c][l]   u0 halo tile, transposed (6.4 KB)
  __shared__ ushort Ys [C_ * YSP];      // [c][dl]  result bounce (6.6 KB, pad 70 -> word-stride 35)
  __shared__ float  Wk0[C_], Wk1[C_], Wk2[C_], CB[C_], DB[C_];

  const int tid = threadIdx.x;
  const int wid = tid >> 6, lane = tid & 63;
  const int lt = blockIdx.x, k = blockIdx.y, b = blockIdx.z;
  const int l0 = lt * 64;

  for (int idx = tid; idx < N_ * 64; idx += 256) {
    const int n = idx >> 6, dl = idx & 63;
    const size_t g = (((size_t)b * K_ + k) * N_ + n) * S_ + l0 + dl;
    Gs[idx] = Bt[g] * Ct[g];
  }
  for (int idx = tid; idx < C_ * N_; idx += 256)
    Ak[idx] = Alog[(size_t)k * C_ * N_ + idx];
  if (tid < C_) {
    Wk0[tid] = convw[(k * C_ + tid) * 9 + 1];   // only kw=1 column is in-bounds (W=1, pad 1)
    Wk1[tid] = convw[(k * C_ + tid) * 9 + 4];
    Wk2[tid] = convw[(k * C_ + tid) * 9 + 7];
    CB [tid] = convb[k * C_ + tid];
    DB [tid] = dbias[k * C_ + tid];
  }
  { // u0 halo tile, transposed into [c][l]: 66 rows x 24 uints, coalesced global reads
    const uint* usrc = reinterpret_cast<const uint*>(u0b);
    for (int idx = tid; idx < 66 * 24; idx += 256) {
      const int l = idx / 24, j = idx - l * 24;
      const int gl = l0 + l - 1;
      uint v = 0;
      if (gl >= 0 && gl < S_) v = usrc[(size_t)((size_t)b * S_ + gl) * 384 + k * 24 + j];
      U0T[(2 * j    ) * U0P + l] = (ushort)(v & 0xffffu);
      U0T[(2 * j + 1) * U0P + l] = (ushort)(v >> 16);
    }
  }
  __syncthreads();

  // G column into registers: reused by all 12 steps (lane-consecutive, conflict-free)
  float g[N_];
#pragma unroll
  for (int n = 0; n < N_; ++n) g[n] = Gs[n * 64 + lane];

  // 12 steps x 4 waves: wave handles channel c = step*4 + wid, lanes span dl = 0..63
  for (int step = 0; step < 12; ++step) {
    const int c = step * 4 + wid;
    float a[N_];
#pragma unroll
    for (int n4 = 0; n4 < 4; ++n4)   // broadcast ds_read_b128 x4 (uniform address)
      *reinterpret_cast<f32x4*>(&a[n4 * 4]) =
          *reinterpret_cast<const f32x4*>(&Ak[c * N_ + n4 * 4]);

    // softplus(delta + bias): direct coalesced global read (c uniform, dl = lane)
    const float dv = delta[((size_t)b * D_ + k * C_ + c) * S_ + l0 + lane] + DB[c];
    const float d  = (dv > 15.f) ? dv : __logf(1.f + __expf(dv));

    // depthwise conv3 + silu (lane-consecutive bf16 reads, conflict-free)
    float x = fmaf(Wk0[c], bf2f(U0T[c * U0P + lane]),
              fmaf(Wk1[c], bf2f(U0T[c * U0P + lane + 1]),
              fmaf(Wk2[c], bf2f(U0T[c * U0P + lane + 2]), CB[c])));
    const float u = x * __builtin_amdgcn_rcpf(1.f + __expf(-x));

    float s = 0.f;
#pragma unroll
    for (int n = 0; n < N_; ++n) s = fmaf(a[n], g[n], s);

    Ys[c * YSP + lane] = f2bf(d * d * u * s);
  }
  __syncthreads();

  // coalesced transposed bf16 store: 48-thread groups write 96 B contiguous
  for (int e = tid; e < C_ * 64; e += 256) {
    const int c = e % C_, dl = e / C_;
    yT[((size_t)((size_t)b * S_ + l0 + dl)) * D_ + k * C_ + c] = Ys[c * YSP + dl];
  }
}

extern "C" void kernel_launch(void* const* d_in, const int* in_sizes, int n_in,
                              void* d_out, int out_size, void* d_ws, size_t ws_size,
                              hipStream_t stream) {
  const float* x      = (const float*)d_in[0];
  const float* in_w   = (const float*)d_in[1];   // (1536,768) — only rows [0,768) used
  const float* in_b   = (const float*)d_in[2];
  const float* convw  = (const float*)d_in[3];
  const float* convb  = (const float*)d_in[4];
  const float* out_w  = (const float*)d_in[5];
  const float* out_b  = (const float*)d_in[6];
  const float* Alog   = (const float*)d_in[7];
  const float* delta  = (const float*)d_in[8];
  const float* Bt     = (const float*)d_in[9];
  const float* Ct     = (const float*)d_in[10];
  const float* dbias  = (const float*)d_in[11];
  float* out = (float*)d_out;

  // workspace: all bf16 (ushort). 3*50.3MB + 2*1.2MB = 153.4 MB
  ushort* xb  = (ushort*)d_ws;
  ushort* u0b = xb  + (size_t)M_ * D_;
  ushort* yTb = u0b + (size_t)M_ * D_;
  ushort* wb1 = yTb + (size_t)M_ * D_;
  ushort* wb2 = wb1 + (size_t)D_ * D_;

  cvt_f32_bf16<<<2048, 256, 0, stream>>>(x,     xb,  M_ * D_ / 4);
  cvt_f32_bf16<<<576,  256, 0, stream>>>(in_w,  wb1, D_ * D_ / 4);   // first 768 rows only
  cvt_f32_bf16<<<576,  256, 0, stream>>>(out_w, wb2, D_ * D_ / 4);

  // GEMM1: u0 = x @ in_w[:768].T + in_b   (bf16 out)
  gemm_mfma_bt<true ><<<1536, 256, 0, stream>>>(xb, wb1, in_b, u0b);
  // fused conv/silu/softplus/einsum/product, bf16 transposed store
  fuse_mid<<<dim3(S_ / 64, K_, B_), 256, 0, stream>>>(u0b, delta, Bt, Ct, Alog, convw, convb, dbias, yTb);
  // GEMM2: out = yT @ out_w.T + out_b   (f32 out)
  gemm_mfma_bt<false><<<1536, 256, 0, stream>>>(yTb, wb2, out_b, out);
}

// Round 4
// 228.055 us; speedup vs baseline: 5.4400x; 1.0094x over previous
//
#include <hip/hip_runtime.h>
#include <math.h>

#define B_  8
#define S_  4096
#define D_  768     // DIM == D_INNER == 768
#define K_  16      // KK
#define C_  48      // CD
#define N_  16      // NS
#define M_  (B_*S_) // 32768 rows

typedef float  f32x4  __attribute__((ext_vector_type(4)));
typedef __bf16 bf16x8 __attribute__((ext_vector_type(8)));

__device__ __forceinline__ ushort f2bf(float f) {
  uint u = __builtin_bit_cast(uint, f);
  u += 0x7FFFu + ((u >> 16) & 1u);      // round-to-nearest-even
  return (ushort)(u >> 16);
}
__device__ __forceinline__ float bf2f(ushort h) {
  return __builtin_bit_cast(float, (uint)h << 16);
}

// ---------------- f32 -> bf16 conversion, all three tensors in one launch
__global__ __launch_bounds__(256)
void cvt_all(const float* __restrict__ x, const float* __restrict__ w1,
             const float* __restrict__ w2, ushort* __restrict__ xb,
             ushort* __restrict__ wb1, ushort* __restrict__ wb2) {
  const int b = blockIdx.x;
  const float* in; ushort* out; int n4, nb, b0;
  if (b < 2048)      { in = x;  out = xb;  n4 = M_ * D_ / 4; nb = 2048; b0 = 0; }
  else if (b < 2624) { in = w1; out = wb1; n4 = D_ * D_ / 4; nb = 576;  b0 = 2048; }
  else               { in = w2; out = wb2; n4 = D_ * D_ / 4; nb = 576;  b0 = 2624; }
  const int stride = nb * 256;
  for (int i = (b - b0) * 256 + threadIdx.x; i < n4; i += stride) {
    float4 v = *reinterpret_cast<const float4*>(in + (size_t)i * 4);
    ushort4 o;
    o.x = f2bf(v.x); o.y = f2bf(v.y); o.z = f2bf(v.z); o.w = f2bf(v.w);
    *reinterpret_cast<ushort4*>(out + (size_t)i * 4) = o;
  }
}

// ---------------- bf16 MFMA GEMM (m97 structure): C[m,n] = sum_k A[m,k]*Bm[n,k] + bias[n]
// 1-D grid of 1536 blocks with XCD-aware swizzle (1536 % 8 == 0 -> bijective).
template<bool OUT_BF16>
__global__ __launch_bounds__(256)
void gemm_mfma_bt(const ushort* __restrict__ A, const ushort* __restrict__ Bm,
                  const float* __restrict__ bias, void* __restrict__ Cc)
{
  __shared__ ushort As[128 * 32];   // 8 KB, linear row-major [row][k] (global_load_lds dest)
  __shared__ ushort Bs[128 * 32];

  const int lin = blockIdx.x;
  const int swz = (lin & 7) * 192 + (lin >> 3);   // XCD-contiguous work chunks
  const int bn  = (swz % 6) * 128;
  const int bm  = (swz / 6) * 128;

  const int tid  = threadIdx.x;
  const int wid  = tid >> 6, lane = tid & 63;
  const int wr   = wid >> 1, wc   = wid & 1;       // wave -> 64x64 quadrant
  const int lr   = lane & 15, lg  = lane >> 4;
  const int srow = lane >> 2;                      // staging: row within 16-row chunk
  const int scol = (lane & 3) * 8;                 // staging: k-element offset

  f32x4 acc[4][4];
#pragma unroll
  for (int i = 0; i < 4; ++i)
#pragma unroll
    for (int j = 0; j < 4; ++j) acc[i][j] = (f32x4){0.f, 0.f, 0.f, 0.f};

  for (int k0 = 0; k0 < 768; k0 += 32) {
#pragma unroll
    for (int jj = 0; jj < 2; ++jj) {
      const int j = wid * 2 + jj;
      const ushort* ga = A  + (size_t)(bm + j * 16 + srow) * 768 + k0 + scol;
      __builtin_amdgcn_global_load_lds(
          (const __attribute__((address_space(1))) void*)ga,
          (__attribute__((address_space(3))) void*)(As + j * 512), 16, 0, 0);
      const ushort* gb = Bm + (size_t)(bn + j * 16 + srow) * 768 + k0 + scol;
      __builtin_amdgcn_global_load_lds(
          (const __attribute__((address_space(1))) void*)gb,
          (__attribute__((address_space(3))) void*)(Bs + j * 512), 16, 0, 0);
    }
    __syncthreads();

    bf16x8 af[4], bfr[4];
    const int ab = (wr * 64 + lr) * 32 + lg * 8;
    const int bb = (wc * 64 + lr) * 32 + lg * 8;
#pragma unroll
    for (int mf = 0; mf < 4; ++mf) af[mf]  = *reinterpret_cast<const bf16x8*>(&As[ab + mf * 512]);
#pragma unroll
    for (int nf = 0; nf < 4; ++nf) bfr[nf] = *reinterpret_cast<const bf16x8*>(&Bs[bb + nf * 512]);
#pragma unroll
    for (int mf = 0; mf < 4; ++mf)
#pragma unroll
      for (int nf = 0; nf < 4; ++nf)
        acc[mf][nf] = __builtin_amdgcn_mfma_f32_16x16x32_bf16(af[mf], bfr[nf], acc[mf][nf], 0, 0, 0);
    __syncthreads();
  }

  // epilogue: C/D layout col = lane&15, row = (lane>>4)*4 + reg
#pragma unroll
  for (int nf = 0; nf < 4; ++nf) {
    const int n  = bn + wc * 64 + nf * 16 + lr;
    const float bv = bias[n];
#pragma unroll
    for (int mf = 0; mf < 4; ++mf) {
      const int m0 = bm + wr * 64 + mf * 16 + lg * 4;
#pragma unroll
      for (int r = 0; r < 4; ++r) {
        const float v = acc[mf][nf][r] + bv;
        if (OUT_BF16) ((ushort*)Cc)[(size_t)(m0 + r) * 768 + n] = f2bf(v);
        else          ((float*) Cc)[(size_t)(m0 + r) * 768 + n] = v;
      }
    }
  }
}

// ---------------- fused middle: conv3+silu, softplus(delta), einsum, d*d*u*s, bf16 transposed store
// Wave-uniform c, dl = lane; 2-deep rotating prefetch of the per-step delta loads.
#define U0P 67
#define YSP 70

__global__ __launch_bounds__(256)
void fuse_mid(const ushort* __restrict__ u0b, const float* __restrict__ delta,
              const float* __restrict__ Bt, const float* __restrict__ Ct,
              const float* __restrict__ Alog, const float* __restrict__ convw,
              const float* __restrict__ convb, const float* __restrict__ dbias,
              ushort* __restrict__ yT)
{
  __shared__ float  Gs [N_ * 64];       // [n][dl]  B*C products (4 KB)
  __shared__ float  Ak [C_ * N_];       // [c][n]   A rows (3 KB, broadcast reads)
  __shared__ ushort U0T[C_ * U0P];      // [c][l]   u0 halo tile, transposed (6.3 KB, pad 67)
  __shared__ ushort Ys [C_ * YSP];      // [c][dl]  result bounce (6.6 KB, pad 70)
  __shared__ float  Wk0[C_], Wk1[C_], Wk2[C_], CB[C_], DB[C_];

  const int tid = threadIdx.x;
  const int wid = tid >> 6, lane = tid & 63;
  const int lt = blockIdx.x, k = blockIdx.y, b = blockIdx.z;
  const int l0 = lt * 64;

  for (int idx = tid; idx < N_ * 64; idx += 256) {
    const int n = idx >> 6, dl = idx & 63;
    const size_t gg = (((size_t)b * K_ + k) * N_ + n) * S_ + l0 + dl;
    Gs[idx] = Bt[gg] * Ct[gg];
  }
  for (int idx = tid; idx < C_ * N_; idx += 256)
    Ak[idx] = Alog[(size_t)k * C_ * N_ + idx];
  if (tid < C_) {
    Wk0[tid] = convw[(k * C_ + tid) * 9 + 1];   // only kw=1 column is in-bounds (W=1, pad 1)
    Wk1[tid] = convw[(k * C_ + tid) * 9 + 4];
    Wk2[tid] = convw[(k * C_ + tid) * 9 + 7];
    CB [tid] = convb[k * C_ + tid];
    DB [tid] = dbias[k * C_ + tid];
  }
  { // u0 halo tile, transposed into [c][l]; incremental div (256 = 10*24 + 16)
    const uint* usrc = reinterpret_cast<const uint*>(u0b);
    int l = tid / 24, j = tid - (tid / 24) * 24;
    for (int idx = tid; idx < 66 * 24; idx += 256) {
      const int gl = l0 + l - 1;
      uint v = 0;
      if (gl >= 0 && gl < S_) v = usrc[((size_t)b * S_ + gl) * 384 + k * 24 + j];
      U0T[(2 * j    ) * U0P + l] = (ushort)(v & 0xffffu);
      U0T[(2 * j + 1) * U0P + l] = (ushort)(v >> 16);
      l += 10; j += 16; if (j >= 24) { j -= 24; l += 1; }
    }
  }
  __syncthreads();

  // G column into registers: reused by all 12 steps (lane-consecutive, conflict-free)
  float g[N_];
#pragma unroll
  for (int n = 0; n < N_; ++n) g[n] = Gs[n * 64 + lane];

  // 2-deep rotating prefetch of delta (c = step*4 + wid, stride 4 rows)
  const float* dp = delta + ((size_t)b * D_ + k * C_ + wid) * S_ + l0 + lane;
  const size_t dstr = (size_t)4 * S_;
  float dn0 = dp[0];
  float dn1 = dp[dstr];

  for (int step = 0; step < 12; ++step) {
    const int c = step * 4 + wid;
    const float dcur = dn0;
    dn0 = dn1;
    dn1 = (step < 10) ? dp[(size_t)(step + 2) * dstr] : 0.f;

    float a[N_];
#pragma unroll
    for (int n4i = 0; n4i < 4; ++n4i)   // broadcast ds_read_b128 x4 (uniform address)
      *reinterpret_cast<f32x4*>(&a[n4i * 4]) =
          *reinterpret_cast<const f32x4*>(&Ak[c * N_ + n4i * 4]);

    const float dv = dcur + DB[c];
    const float d  = (dv > 15.f) ? dv : __logf(1.f + __expf(dv));   // softplus

    float xx = fmaf(Wk0[c], bf2f(U0T[c * U0P + lane]),
               fmaf(Wk1[c], bf2f(U0T[c * U0P + lane + 1]),
               fmaf(Wk2[c], bf2f(U0T[c * U0P + lane + 2]), CB[c])));
    const float u = xx * __builtin_amdgcn_rcpf(1.f + __expf(-xx));  // silu

    float s = 0.f;
#pragma unroll
    for (int n = 0; n < N_; ++n) s = fmaf(a[n], g[n], s);

    Ys[c * YSP + lane] = f2bf(d * d * u * s);
  }
  __syncthreads();

  // coalesced transposed bf16 store; incremental div (256 = 5*48 + 16)
  {
    int dl = tid / 48, c = tid - (tid / 48) * 48;
    for (int e = tid; e < C_ * 64; e += 256) {
      yT[((size_t)b * S_ + l0 + dl) * D_ + k * C_ + c] = Ys[c * YSP + dl];
      dl += 5; c += 16; if (c >= 48) { c -= 48; dl += 1; }
    }
  }
}

extern "C" void kernel_launch(void* const* d_in, const int* in_sizes, int n_in,
                              void* d_out, int out_size, void* d_ws, size_t ws_size,
                              hipStream_t stream) {
  const float* x      = (const float*)d_in[0];
  const float* in_w   = (const float*)d_in[1];   // (1536,768) — only rows [0,768) used
  const float* in_b   = (const float*)d_in[2];
  const float* convw  = (const float*)d_in[3];
  const float* convb  = (const float*)d_in[4];
  const float* out_w  = (const float*)d_in[5];
  const float* out_b  = (const float*)d_in[6];
  const float* Alog   = (const float*)d_in[7];
  const float* delta  = (const float*)d_in[8];
  const float* Bt     = (const float*)d_in[9];
  const float* Ct     = (const float*)d_in[10];
  const float* dbias  = (const float*)d_in[11];
  float* out = (float*)d_out;

  // workspace: all bf16 (ushort). 3*50.3MB + 2*1.2MB = 153.4 MB
  ushort* xb  = (ushort*)d_ws;
  ushort* u0b = xb  + (size_t)M_ * D_;
  ushort* yTb = u0b + (size_t)M_ * D_;
  ushort* wb1 = yTb + (size_t)M_ * D_;
  ushort* wb2 = wb1 + (size_t)D_ * D_;

  cvt_all<<<3200, 256, 0, stream>>>(x, in_w, out_w, xb, wb1, wb2);

  // GEMM1: u0 = x @ in_w[:768].T + in_b   (bf16 out)
  gemm_mfma_bt<true ><<<1536, 256, 0, stream>>>(xb, wb1, in_b, u0b);
  // fused conv/silu/softplus/einsum/product, bf16 transposed store
  fuse_mid<<<dim3(S_ / 64, K_, B_), 256, 0, stream>>>(u0b, delta, Bt, Ct, Alog, convw, convb, dbias, yTb);
  // GEMM2: out = yT @ out_w.T + out_b   (f32 out)
  gemm_mfma_bt<false><<<1536, 256, 0, stream>>>(yTb, wb2, out_b, out);
}